// Round 6
// baseline (4700.049 us; speedup 1.0000x reference)
//
#include <hip/hip_runtime.h>

#define BB 1024
#define NN 81
#define EE 1620
#define HH 128
#define G3 384
#define NSTEPS 8

#define HSTR 132     // hRM/smRM/hid row stride (floats), 528B (16B-mult)
#define ABSTR 260    // hAB row stride (floats), 1040B

typedef __attribute__((ext_vector_type(4))) float f32x4;
typedef __attribute__((ext_vector_type(2))) float f32x2;

// ---- LDS float offsets ----
#define F_H     0            // hRM 81 x 132 = 10692
#define F_R2    10692        // 21060: union{ xs+win | hAB 81x260 | smRM 81x132 | hid 81x132 }
#define F_GOFF  31752        // 82 ints
#define F_GSEND 31834        // 1620 ushorts (810 float slots)
#define F_BM1   32644        // 128
#define F_BASE  32772        // 512
#define F_EXT   33284        // 512
#define F_G80   33796        // 512 (row-80 gate staging)
#define F_TOT   34308
#define LDS_BYTES (F_TOT * 4)   // 137232 bytes

// ---------------------------------------------------------------------------
// prep_graph: CSR by receiver (int32 edge input) — verified R2/R4/R5.
// ---------------------------------------------------------------------------
__global__ __launch_bounds__(128) void prep_graph(const int* __restrict__ ei,
                                                  int* __restrict__ goff,
                                                  int* __restrict__ gsend) {
    __shared__ int eis[2 * EE];
    __shared__ int cs[NN];
    __shared__ int offs[NN + 1];
    int tid = threadIdx.x;
    for (int i = tid; i < 2 * EE; i += 128) eis[i] = ei[i];
    __syncthreads();
    if (tid < NN) {
        int c = 0;
        for (int e = 0; e < EE; e++) if (eis[EE + e] == tid) c++;
        cs[tid] = c;
    }
    __syncthreads();
    if (tid == 0) {
        int o = 0;
        for (int r = 0; r < NN; r++) { offs[r] = o; o += cs[r]; }
        offs[NN] = o;
    }
    __syncthreads();
    if (tid < NN) {
        int pos = offs[tid];
        for (int e = 0; e < EE; e++) {
            if (eis[EE + e] == tid) gsend[pos++] = eis[e];
        }
        goff[tid] = offs[tid];
    }
    if (tid == 0) goff[NN] = offs[NN];
}

// ---------------------------------------------------------------------------
// prep_wc: Wc[c][o] = sum_m W_ih[c][m] * W_m2[m][o]   (384 x 128)
// ---------------------------------------------------------------------------
__global__ __launch_bounds__(256) void prep_wc(const float* __restrict__ W_ih,
                                               const float* __restrict__ W_m2,
                                               float* __restrict__ Wc) {
    int idx = blockIdx.x * 256 + threadIdx.x;
    if (idx >= G3 * HH) return;
    int c = idx >> 7, o = idx & 127;
    float acc = 0.f;
    for (int m = 0; m < HH; m++) acc += W_ih[c * HH + m] * W_m2[m * HH + o];
    Wc[idx] = acc;
}

// ---------------------------------------------------------------------------
// prep_bias: base[512], ext[512]
// ---------------------------------------------------------------------------
__global__ __launch_bounds__(256) void prep_bias(const float* __restrict__ W_ih,
                                                 const float* __restrict__ b_m2,
                                                 const float* __restrict__ b_ih,
                                                 const float* __restrict__ b_hh,
                                                 float* __restrict__ basev,
                                                 float* __restrict__ extv) {
    int c = blockIdx.x * 256 + threadIdx.x;
    if (c >= 512) return;
    float base, ext;
    if (c < 384) {
        float bwc = 0.f;
        for (int m = 0; m < HH; m++) bwc += W_ih[c * HH + m] * b_m2[m];
        ext = bwc;
        base = (c < 256) ? (b_ih[c] + b_hh[c]) : b_ih[c];
    } else {
        ext = 0.f;
        base = b_hh[c - 128];
    }
    basev[c] = base;
    extv[c] = ext;
}

// ---------------------------------------------------------------------------
// prep_w1t: W1t[k][c] (128 x 256)
// ---------------------------------------------------------------------------
__global__ __launch_bounds__(256) void prep_w1t(const float* __restrict__ W_m1,
                                                float* __restrict__ W1t) {
    int idx = blockIdx.x * 256 + threadIdx.x;
    if (idx >= 128 * 256) return;
    int k = idx >> 8, c = idx & 255;
    W1t[idx] = (c < 128) ? W_m1[c * 256 + k] : W_m1[(c - 128) * 256 + 128 + k];
}

// ---------------------------------------------------------------------------
// prep_wg2: B2[k][c] (256 x 384): k<128 -> Wc[c][k] ; else W_hh[c][k-128]
// ---------------------------------------------------------------------------
__global__ __launch_bounds__(256) void prep_wg2(const float* __restrict__ Wc,
                                                const float* __restrict__ W_hh,
                                                float* __restrict__ Wg2) {
    int idx = blockIdx.x * 256 + threadIdx.x;
    if (idx >= 256 * G3) return;
    int k = idx / G3;
    int c = idx - k * G3;
    Wg2[idx] = (k < 128) ? Wc[c * HH + k] : W_hh[c * HH + (k - 128)];
}

// ---------------------------------------------------------------------------
// prep_wo1t: Wo1t[k][c] = W_o1[c][k]   (128 x 128)
// ---------------------------------------------------------------------------
__global__ __launch_bounds__(256) void prep_wo1t(const float* __restrict__ W_o1,
                                                 float* __restrict__ Wo1t) {
    int idx = blockIdx.x * 256 + threadIdx.x;
    if (idx >= 128 * 128) return;
    int k = idx >> 7, c = idx & 127;
    Wo1t[idx] = W_o1[c * HH + k];
}

// ---------------------------------------------------------------------------
// fused_rrn: one workgroup per puzzle, 1024 threads (16 waves), fp32.
// GEMM map: wave w owns rows {w+16i, i<5}; lane owns col pair {2l,2l+1} per
// gate group. A = uniform LDS broadcast (f32x4/4k); B = coalesced dwordx2.
// Row 80 handled by tail on waves 0..2 (+ staged epilogue on wave 3).
// ---------------------------------------------------------------------------
__global__ __launch_bounds__(1024) void fused_rrn(
    const float* __restrict__ x,
    const float* __restrict__ W_in, const float* __restrict__ b_in,
    const float* __restrict__ b_m1,
    const float* __restrict__ W1t, const float* __restrict__ Wg2,
    const float* __restrict__ basev, const float* __restrict__ extv,
    const float* __restrict__ Wo1t, const float* __restrict__ b_o1,
    const float* __restrict__ W_o2, const float* __restrict__ b_o2,
    const int* __restrict__ goff_g, const int* __restrict__ gsend_g,
    float* __restrict__ out)
{
    extern __shared__ float smf[];
    float* hRM  = smf + F_H;
    float* reg2 = smf + F_R2;
    int*   goffL = (int*)(smf + F_GOFF);
    unsigned short* gsendL = (unsigned short*)(smf + F_GSEND);
    float* bm1L  = smf + F_BM1;
    float* baseL = smf + F_BASE;
    float* extL  = smf + F_EXT;
    float* g80   = smf + F_G80;

    const int t  = threadIdx.x;
    const int b  = blockIdx.x;
    const int w  = t >> 6;            // wave 0..15
    const int l  = t & 63;
    const int l2 = 2 * l;
    const int rW = t & 31;            // edge-phase row lane
    const int q  = t >> 5;            // edge-phase feat quad
    const int fq = 4 * q;

    // ---- stage misc + x/W_in (into reg2; used once) ----
    float* xsL  = reg2;          // 810
    float* winL = reg2 + 810;    // 1280
    for (int i = t; i < NN + 1; i += 1024) goffL[i] = goff_g[i];
    for (int i = t; i < EE; i += 1024) gsendL[i] = (unsigned short)gsend_g[i];
    if (t < 512) { baseL[t] = basev[t]; extL[t] = extv[t]; }
    if (t < 128) bm1L[t] = b_m1[t];
    for (int i = t; i < NN * 10; i += 1024) xsL[i] = x[(long)b * (NN * 10) + i];
    for (int i = t; i < HH * 10; i += 1024) winL[i] = W_in[i];
    __syncthreads();

    // ---- input projection: hRM[r][m] ----
    for (int idx = t; idx < NN * HH; idx += 1024) {
        int r = idx >> 7, m = idx & 127;
        float acc = b_in[m];
#pragma unroll
        for (int k = 0; k < 10; k++) acc += xsL[r * 10 + k] * winL[m * 10 + k];
        hRM[r * HSTR + m] = acc;
    }
    __syncthreads();

    int rb[5];
#pragma unroll
    for (int i = 0; i < 5; i++) rb[i] = (w + 16 * i) * HSTR;

    // ======================= 8 message-passing steps =======================
    for (int step = 0; step < NSTEPS; step++) {
        // ---------- GEMM1: hAB = h @ W1^T ----------
        {
            float a1[5][4];
#pragma unroll
            for (int i = 0; i < 5; i++)
#pragma unroll
                for (int c = 0; c < 4; c++) a1[i][c] = 0.f;
            float ta1[2] = {0.f, 0.f};
            const bool tw = (w < 2);
            for (int kc = 0; kc < 128; kc += 4) {
                f32x4 a4[5];
#pragma unroll
                for (int i = 0; i < 5; i++) a4[i] = *(const f32x4*)(hRM + rb[i] + kc);
                f32x4 a80;
                if (tw) a80 = *(const f32x4*)(hRM + 80 * HSTR + kc);
#pragma unroll
                for (int j = 0; j < 4; j++) {
                    const float* Bk = W1t + (kc + j) * 256;
                    f32x2 b01 = *(const f32x2*)(Bk + l2);
                    f32x2 b23 = *(const f32x2*)(Bk + 128 + l2);
#pragma unroll
                    for (int i = 0; i < 5; i++) {
                        float a = a4[i][j];
                        a1[i][0] = fmaf(a, b01[0], a1[i][0]);
                        a1[i][1] = fmaf(a, b01[1], a1[i][1]);
                        a1[i][2] = fmaf(a, b23[0], a1[i][2]);
                        a1[i][3] = fmaf(a, b23[1], a1[i][3]);
                    }
                    if (tw) {
                        f32x2 bT = *(const f32x2*)(Bk + 2 * t);
                        ta1[0] = fmaf(a80[j], bT[0], ta1[0]);
                        ta1[1] = fmaf(a80[j], bT[1], ta1[1]);
                    }
                }
            }
            float* hAB = reg2;
#pragma unroll
            for (int i = 0; i < 5; i++) {
                int row = w + 16 * i;
                f32x2 v0 = {a1[i][0], a1[i][1]};
                f32x2 v1 = {a1[i][2], a1[i][3]};
                *(f32x2*)(hAB + row * ABSTR + l2) = v0;
                *(f32x2*)(hAB + row * ABSTR + 128 + l2) = v1;
            }
            if (tw) {
                f32x2 tv = {ta1[0], ta1[1]};
                *(f32x2*)(hAB + 80 * ABSTR + 2 * t) = tv;
            }
        }
        __syncthreads();   // B1: hAB ready

        // ---------- edge aggregation ----------
        float sv[3][4];
        {
            float bq[4];
#pragma unroll
            for (int j = 0; j < 4; j++) bq[j] = bm1L[fq + j];
#pragma unroll
            for (int s = 0; s < 3; s++) {
                int row = rW + 32 * s;
                if (row >= NN) { sv[s][0] = sv[s][1] = sv[s][2] = sv[s][3] = 0.f; continue; }
                int e0 = goffL[row], e1 = goffL[row + 1];
                f32x4 hb = *(const f32x4*)(reg2 + row * ABSTR + 128 + fq);
                float hbb[4], ac[4];
#pragma unroll
                for (int j = 0; j < 4; j++) { hbb[j] = hb[j] + bq[j]; ac[j] = 0.f; }
                for (int e = e0; e < e1; e++) {
                    int sn = gsendL[e];
                    f32x4 av = *(const f32x4*)(reg2 + sn * ABSTR + fq);
#pragma unroll
                    for (int j = 0; j < 4; j++) ac[j] += fmaxf(av[j] + hbb[j], 0.f);
                }
#pragma unroll
                for (int j = 0; j < 4; j++) sv[s][j] = ac[j];
            }
        }
        __syncthreads();   // B2: hAB reads done, reg2 reusable as smRM
        {
#pragma unroll
            for (int s = 0; s < 3; s++) {
                int row = rW + 32 * s;
                if (row >= NN) continue;
                f32x4 svv = {sv[s][0], sv[s][1], sv[s][2], sv[s][3]};
                *(f32x4*)(reg2 + row * HSTR + fq) = svv;
            }
        }
        __syncthreads();   // B3: smRM ready

        // ---------- GEMM2: gates ----------
        {
            float rr[5][2], zz[5][2], ni[5][2], nh[5][2];
#pragma unroll
            for (int i = 0; i < 5; i++) {
                rr[i][0] = rr[i][1] = 0.f; zz[i][0] = zz[i][1] = 0.f;
                ni[i][0] = ni[i][1] = 0.f; nh[i][0] = nh[i][1] = 0.f;
            }
            float t4a[2] = {0.f, 0.f}, t4b[2] = {0.f, 0.f};
            const bool tw = (w < 3);
            const float* smRM = reg2;

            // phase 1: A = sm, B rows 0..127 -> rr, zz, ni
            for (int kc = 0; kc < 128; kc += 4) {
                f32x4 a4[5];
#pragma unroll
                for (int i = 0; i < 5; i++) a4[i] = *(const f32x4*)(smRM + rb[i] + kc);
                f32x4 a80;
                if (tw) a80 = *(const f32x4*)(smRM + 80 * HSTR + kc);
#pragma unroll
                for (int j = 0; j < 4; j++) {
                    const float* Bk = Wg2 + (kc + j) * G3;
                    f32x2 bR = *(const f32x2*)(Bk + l2);
                    f32x2 bZ = *(const f32x2*)(Bk + 128 + l2);
                    f32x2 bN = *(const f32x2*)(Bk + 256 + l2);
#pragma unroll
                    for (int i = 0; i < 5; i++) {
                        float a = a4[i][j];
                        rr[i][0] = fmaf(a, bR[0], rr[i][0]);
                        rr[i][1] = fmaf(a, bR[1], rr[i][1]);
                        zz[i][0] = fmaf(a, bZ[0], zz[i][0]);
                        zz[i][1] = fmaf(a, bZ[1], zz[i][1]);
                        ni[i][0] = fmaf(a, bN[0], ni[i][0]);
                        ni[i][1] = fmaf(a, bN[1], ni[i][1]);
                    }
                    if (tw) {
                        f32x2 bT = *(const f32x2*)(Bk + 2 * t);
                        t4a[0] = fmaf(a80[j], bT[0], t4a[0]);
                        t4a[1] = fmaf(a80[j], bT[1], t4a[1]);
                    }
                }
            }
            // phase 2: A = h, B rows 128..255 -> rr, zz, nh
            for (int kc = 0; kc < 128; kc += 4) {
                f32x4 a4[5];
#pragma unroll
                for (int i = 0; i < 5; i++) a4[i] = *(const f32x4*)(hRM + rb[i] + kc);
                f32x4 a80;
                if (tw) a80 = *(const f32x4*)(hRM + 80 * HSTR + kc);
#pragma unroll
                for (int j = 0; j < 4; j++) {
                    const float* Bk = Wg2 + (128 + kc + j) * G3;
                    f32x2 bR = *(const f32x2*)(Bk + l2);
                    f32x2 bZ = *(const f32x2*)(Bk + 128 + l2);
                    f32x2 bN = *(const f32x2*)(Bk + 256 + l2);
#pragma unroll
                    for (int i = 0; i < 5; i++) {
                        float a = a4[i][j];
                        rr[i][0] = fmaf(a, bR[0], rr[i][0]);
                        rr[i][1] = fmaf(a, bR[1], rr[i][1]);
                        zz[i][0] = fmaf(a, bZ[0], zz[i][0]);
                        zz[i][1] = fmaf(a, bZ[1], zz[i][1]);
                        nh[i][0] = fmaf(a, bN[0], nh[i][0]);
                        nh[i][1] = fmaf(a, bN[1], nh[i][1]);
                    }
                    if (tw) {
                        f32x2 bT = *(const f32x2*)(Bk + 2 * t);
                        if (w == 2) {
                            t4b[0] = fmaf(a80[j], bT[0], t4b[0]);
                            t4b[1] = fmaf(a80[j], bT[1], t4b[1]);
                        } else {
                            t4a[0] = fmaf(a80[j], bT[0], t4a[0]);
                            t4a[1] = fmaf(a80[j], bT[1], t4a[1]);
                        }
                    }
                }
            }
            // stage row-80 gates: w0->r(0..127), w1->z(128..255), w2->ni(256..383)+nh(384..511)
            if (tw) {
                f32x2 va = {t4a[0], t4a[1]};
                *(f32x2*)(g80 + 2 * t) = va;
                if (w == 2) {
                    f32x2 vb = {t4b[0], t4b[1]};
                    *(f32x2*)(g80 + 128 + 2 * t) = vb;
                }
            }
            __syncthreads();   // B4: all smRM/hRM reads + g80 stage done

            // ---- GRU epilogue (main rows) ----
            f32x2 base0 = *(const f32x2*)(baseL + l2);
            f32x2 ext0  = *(const f32x2*)(extL + l2);
            f32x2 base1 = *(const f32x2*)(baseL + 128 + l2);
            f32x2 ext1  = *(const f32x2*)(extL + 128 + l2);
            f32x2 base2 = *(const f32x2*)(baseL + 256 + l2);
            f32x2 ext2  = *(const f32x2*)(extL + 256 + l2);
            f32x2 base3 = *(const f32x2*)(baseL + 384 + l2);
#pragma unroll
            for (int i = 0; i < 5; i++) {
                int row = w + 16 * i;
                float cf = (float)(goffL[row + 1] - goffL[row]);
                f32x2 ho = *(const f32x2*)(hRM + row * HSTR + l2);
                float hn[2];
#pragma unroll
                for (int c = 0; c < 2; c++) {
                    float g0 = rr[i][c] + base0[c] + cf * ext0[c];
                    float g1 = zz[i][c] + base1[c] + cf * ext1[c];
                    float g2 = ni[i][c] + base2[c] + cf * ext2[c];
                    float g3 = nh[i][c] + base3[c];
                    float rg_ = 1.f / (1.f + __expf(-g0));
                    float z   = 1.f / (1.f + __expf(-g1));
                    float npre = g2 + rg_ * g3;
                    float ax = fabsf(npre);
                    float e  = __expf(-2.f * ax);
                    float tt = (1.f - e) / (1.f + e);
                    float n  = copysignf(tt, npre);
                    hn[c] = (1.f - z) * n + z * ho[c];
                }
                f32x2 hv = {hn[0], hn[1]};
                *(f32x2*)(hRM + row * HSTR + l2) = hv;
            }
            // ---- row 80 epilogue (wave 3) ----
            if (w == 3) {
                float cf = (float)(goffL[81] - goffL[80]);
                f32x2 gr  = *(const f32x2*)(g80 + l2);
                f32x2 gz  = *(const f32x2*)(g80 + 128 + l2);
                f32x2 gni = *(const f32x2*)(g80 + 256 + l2);
                f32x2 gnh = *(const f32x2*)(g80 + 384 + l2);
                f32x2 ho  = *(const f32x2*)(hRM + 80 * HSTR + l2);
                float hn[2];
#pragma unroll
                for (int c = 0; c < 2; c++) {
                    float g0 = gr[c] + base0[c] + cf * ext0[c];
                    float g1 = gz[c] + base1[c] + cf * ext1[c];
                    float g2 = gni[c] + base2[c] + cf * ext2[c];
                    float g3 = gnh[c] + base3[c];
                    float rg_ = 1.f / (1.f + __expf(-g0));
                    float z   = 1.f / (1.f + __expf(-g1));
                    float npre = g2 + rg_ * g3;
                    float ax = fabsf(npre);
                    float e  = __expf(-2.f * ax);
                    float tt = (1.f - e) / (1.f + e);
                    float n  = copysignf(tt, npre);
                    hn[c] = (1.f - z) * n + z * ho[c];
                }
                f32x2 hv = {hn[0], hn[1]};
                *(f32x2*)(hRM + 80 * HSTR + l2) = hv;
            }
        }
        __syncthreads();   // B5: new h visible
    }

    // ======================= output head =======================
    {
        float a3[5][2];
#pragma unroll
        for (int i = 0; i < 5; i++) { a3[i][0] = 0.f; a3[i][1] = 0.f; }
        float ta3[2] = {0.f, 0.f};
        const bool tw = (w == 0);
        for (int kc = 0; kc < 128; kc += 4) {
            f32x4 a4[5];
#pragma unroll
            for (int i = 0; i < 5; i++) a4[i] = *(const f32x4*)(hRM + rb[i] + kc);
            f32x4 a80;
            if (tw) a80 = *(const f32x4*)(hRM + 80 * HSTR + kc);
#pragma unroll
            for (int j = 0; j < 4; j++) {
                const float* Bk = Wo1t + (kc + j) * 128;
                f32x2 bb = *(const f32x2*)(Bk + l2);
#pragma unroll
                for (int i = 0; i < 5; i++) {
                    float a = a4[i][j];
                    a3[i][0] = fmaf(a, bb[0], a3[i][0]);
                    a3[i][1] = fmaf(a, bb[1], a3[i][1]);
                }
                if (tw) {
                    ta3[0] = fmaf(a80[j], bb[0], ta3[0]);
                    ta3[1] = fmaf(a80[j], bb[1], ta3[1]);
                }
            }
        }
        f32x2 bo = *(const f32x2*)(b_o1 + l2);
#pragma unroll
        for (int i = 0; i < 5; i++) {
            int row = w + 16 * i;
            f32x2 hv = {fmaxf(a3[i][0] + bo[0], 0.f), fmaxf(a3[i][1] + bo[1], 0.f)};
            *(f32x2*)(reg2 + row * HSTR + l2) = hv;
        }
        if (tw) {
            f32x2 hv = {fmaxf(ta3[0] + bo[0], 0.f), fmaxf(ta3[1] + bo[1], 0.f)};
            *(f32x2*)(reg2 + 80 * HSTR + l2) = hv;
        }
    }
    __syncthreads();
    // stage W_o2/b_o2 into hRM area (dead)
    {
        float* wo2L = hRM;
        float* bo2L = hRM + 1152;
        for (int i = t; i < 9 * HH; i += 1024) wo2L[i] = W_o2[i];
        if (t < 9) bo2L[t] = b_o2[t];
    }
    __syncthreads();
    {
        const float* wo2L = hRM;
        const float* bo2L = hRM + 1152;
        for (int idx = t; idx < NN * 9; idx += 1024) {
            int r = idx / 9, qq = idx - 9 * r;
            float acc = bo2L[qq];
            const float* hrow = reg2 + r * HSTR;
            const float* wrow = wo2L + qq * HH;
            for (int k = 0; k < HH; k++) acc = fmaf(hrow[k], wrow[k], acc);
            out[((long)b * NN + r) * 9 + qq] = acc;
        }
    }
}

// ---------------------------------------------------------------------------
extern "C" void kernel_launch(void* const* d_in, const int* in_sizes, int n_in,
                              void* d_out, int out_size, void* d_ws, size_t ws_size,
                              hipStream_t stream) {
    const float* x      = (const float*)d_in[0];
    const int* ei       = (const int*)d_in[1];
    const float* W_in   = (const float*)d_in[2];
    const float* b_in   = (const float*)d_in[3];
    const float* W_m1   = (const float*)d_in[4];
    const float* b_m1   = (const float*)d_in[5];
    const float* W_m2   = (const float*)d_in[6];
    const float* b_m2   = (const float*)d_in[7];
    const float* W_ih   = (const float*)d_in[8];
    const float* W_hh   = (const float*)d_in[9];
    const float* b_ih   = (const float*)d_in[10];
    const float* b_hh   = (const float*)d_in[11];
    const float* W_o1   = (const float*)d_in[12];
    const float* b_o1   = (const float*)d_in[13];
    const float* W_o2   = (const float*)d_in[14];
    const float* b_o2   = (const float*)d_in[15];
    float* out = (float*)d_out;

    char* ws = (char*)d_ws;
    size_t off = 0;
    auto alloc = [&](size_t bytes) -> char* {
        char* p = ws + off;
        off += (bytes + 255) & ~(size_t)255;
        return p;
    };
    float* Wc    = (float*)alloc((size_t)G3 * HH * 4);
    float* W1t   = (float*)alloc(128 * 256 * 4);
    float* Wg2   = (float*)alloc(256 * G3 * 4);
    float* Wo1t  = (float*)alloc(128 * 128 * 4);
    float* basev = (float*)alloc(512 * 4);
    float* extv  = (float*)alloc(512 * 4);
    int* goff    = (int*)alloc((NN + 1) * 4);
    int* gsend   = (int*)alloc(EE * 4);

    prep_graph<<<1, 128, 0, stream>>>(ei, goff, gsend);
    prep_wc<<<(G3 * HH + 255) / 256, 256, 0, stream>>>(W_ih, W_m2, Wc);
    prep_bias<<<2, 256, 0, stream>>>(W_ih, b_m2, b_ih, b_hh, basev, extv);
    prep_w1t<<<128, 256, 0, stream>>>(W_m1, W1t);
    prep_wg2<<<(256 * G3 + 255) / 256, 256, 0, stream>>>(Wc, W_hh, Wg2);
    prep_wo1t<<<64, 256, 0, stream>>>(W_o1, Wo1t);

    (void)hipFuncSetAttribute((const void*)fused_rrn,
                              hipFuncAttributeMaxDynamicSharedMemorySize,
                              (int)LDS_BYTES);
    fused_rrn<<<BB, 1024, LDS_BYTES, stream>>>(
        x, W_in, b_in, b_m1, W1t, Wg2, basev, extv,
        Wo1t, b_o1, W_o2, b_o2, goff, gsend, out);
}

// Round 7
// 3798.668 us; speedup vs baseline: 1.2373x; 1.2373x over previous
//
#include <hip/hip_runtime.h>

#define BB 1024
#define NN 81
#define EE 1620
#define HH 128
#define G3 384
#define NSTEPS 8

#define HSTR 132     // hRM/smRM/hid row stride (floats)
#define ABSTR 260    // hAB row stride (floats)

typedef __attribute__((ext_vector_type(4))) float f32x4;

// ---- LDS float offsets ----
#define F_H     0            // hRM 81 x 132 = 10692
#define F_R2    10692        // 21060: union{ xs+win | hAB 81x260 | smRM 81x132 | hid 81x132 }
#define F_GOFF  31752        // 82 ints
#define F_GSEND 31834        // 1620 ushorts (810 float slots)
#define F_BM1   32644        // 128
#define F_BASE  32772        // 512
#define F_EXT   33284        // 512
#define F_TOT   33796
#define LDS_BYTES (F_TOT * 4)   // 135184 bytes

// ---------------------------------------------------------------------------
// prep_graph: CSR by receiver (int32 edge input) — verified R2/R4/R5/R6.
// ---------------------------------------------------------------------------
__global__ __launch_bounds__(128) void prep_graph(const int* __restrict__ ei,
                                                  int* __restrict__ goff,
                                                  int* __restrict__ gsend) {
    __shared__ int eis[2 * EE];
    __shared__ int cs[NN];
    __shared__ int offs[NN + 1];
    int tid = threadIdx.x;
    for (int i = tid; i < 2 * EE; i += 128) eis[i] = ei[i];
    __syncthreads();
    if (tid < NN) {
        int c = 0;
        for (int e = 0; e < EE; e++) if (eis[EE + e] == tid) c++;
        cs[tid] = c;
    }
    __syncthreads();
    if (tid == 0) {
        int o = 0;
        for (int r = 0; r < NN; r++) { offs[r] = o; o += cs[r]; }
        offs[NN] = o;
    }
    __syncthreads();
    if (tid < NN) {
        int pos = offs[tid];
        for (int e = 0; e < EE; e++) {
            if (eis[EE + e] == tid) gsend[pos++] = eis[e];
        }
        goff[tid] = offs[tid];
    }
    if (tid == 0) goff[NN] = offs[NN];
}

// ---------------------------------------------------------------------------
// prep_wc: Wc[c][o] = sum_m W_ih[c][m] * W_m2[m][o]   (384 x 128)
// ---------------------------------------------------------------------------
__global__ __launch_bounds__(256) void prep_wc(const float* __restrict__ W_ih,
                                               const float* __restrict__ W_m2,
                                               float* __restrict__ Wc) {
    int idx = blockIdx.x * 256 + threadIdx.x;
    if (idx >= G3 * HH) return;
    int c = idx >> 7, o = idx & 127;
    float acc = 0.f;
    for (int m = 0; m < HH; m++) acc += W_ih[c * HH + m] * W_m2[m * HH + o];
    Wc[idx] = acc;
}

// ---------------------------------------------------------------------------
// prep_bias: base[512], ext[512]
// ---------------------------------------------------------------------------
__global__ __launch_bounds__(256) void prep_bias(const float* __restrict__ W_ih,
                                                 const float* __restrict__ b_m2,
                                                 const float* __restrict__ b_ih,
                                                 const float* __restrict__ b_hh,
                                                 float* __restrict__ basev,
                                                 float* __restrict__ extv) {
    int c = blockIdx.x * 256 + threadIdx.x;
    if (c >= 512) return;
    float base, ext;
    if (c < 384) {
        float bwc = 0.f;
        for (int m = 0; m < HH; m++) bwc += W_ih[c * HH + m] * b_m2[m];
        ext = bwc;
        base = (c < 256) ? (b_ih[c] + b_hh[c]) : b_ih[c];
    } else {
        ext = 0.f;
        base = b_hh[c - 128];
    }
    basev[c] = base;
    extv[c] = ext;
}

// ---------------------------------------------------------------------------
// prep_w1t: W1t[k][c] (128 x 256)
// ---------------------------------------------------------------------------
__global__ __launch_bounds__(256) void prep_w1t(const float* __restrict__ W_m1,
                                                float* __restrict__ W1t) {
    int idx = blockIdx.x * 256 + threadIdx.x;
    if (idx >= 128 * 256) return;
    int k = idx >> 8, c = idx & 255;
    W1t[idx] = (c < 128) ? W_m1[c * 256 + k] : W_m1[(c - 128) * 256 + 128 + k];
}

// ---------------------------------------------------------------------------
// prep_wg2: Wg2[k][c] (256 x 384): k<128 -> Wc[c][k] ; else W_hh[c][k-128]
// ---------------------------------------------------------------------------
__global__ __launch_bounds__(256) void prep_wg2(const float* __restrict__ Wc,
                                                const float* __restrict__ W_hh,
                                                float* __restrict__ Wg2) {
    int idx = blockIdx.x * 256 + threadIdx.x;
    if (idx >= 256 * G3) return;
    int k = idx / G3;
    int c = idx - k * G3;
    Wg2[idx] = (k < 128) ? Wc[c * HH + k] : W_hh[c * HH + (k - 128)];
}

// ---------------------------------------------------------------------------
// prep_wo1t: Wo1t[k][c] = W_o1[c][k]   (128 x 128)
// ---------------------------------------------------------------------------
__global__ __launch_bounds__(256) void prep_wo1t(const float* __restrict__ W_o1,
                                                 float* __restrict__ Wo1t) {
    int idx = blockIdx.x * 256 + threadIdx.x;
    if (idx >= 128 * 128) return;
    int k = idx >> 7, c = idx & 127;
    Wo1t[idx] = W_o1[c * HH + k];
}

// ---------------------------------------------------------------------------
// fused_rrn: one workgroup per puzzle, 1024 threads (16 waves), fp32.
// GEMM map: thread (g = t>>7, c = t&127) owns rows [10g, 10g+nR) for ALL its
// gate columns {c, 128+c, 256+c}. A = wave-uniform LDS broadcast; B = global
// dword coalesced (256B/wave), reused across 10-11 rows in registers
// (B-bytes per FMA halved vs R6 -> L1 BW below VALU time).
// ---------------------------------------------------------------------------
__global__ __launch_bounds__(1024) void fused_rrn(
    const float* __restrict__ x,
    const float* __restrict__ W_in, const float* __restrict__ b_in,
    const float* __restrict__ b_m1,
    const float* __restrict__ W1t, const float* __restrict__ Wg2,
    const float* __restrict__ basev, const float* __restrict__ extv,
    const float* __restrict__ Wo1t, const float* __restrict__ b_o1,
    const float* __restrict__ W_o2, const float* __restrict__ b_o2,
    const int* __restrict__ goff_g, const int* __restrict__ gsend_g,
    float* __restrict__ out)
{
    extern __shared__ float smf[];
    float* hRM  = smf + F_H;
    float* reg2 = smf + F_R2;
    int*   goffL = (int*)(smf + F_GOFF);
    unsigned short* gsendL = (unsigned short*)(smf + F_GSEND);
    float* bm1L  = smf + F_BM1;
    float* baseL = smf + F_BASE;
    float* extL  = smf + F_EXT;

    const int t  = threadIdx.x;
    const int b  = blockIdx.x;
    const int c  = t & 127;           // gate column
    const int g  = t >> 7;            // row group 0..7
    const int rowBase = g * 10;
    const int nR = (g == 7) ? 11 : 10;
    const int rW = t & 31;            // edge-phase row lane
    const int q  = t >> 5;            // edge-phase feat quad
    const int fq = 4 * q;

    // ---- stage misc + x/W_in (into reg2; used once) ----
    float* xsL  = reg2;          // 810
    float* winL = reg2 + 810;    // 1280
    for (int i = t; i < NN + 1; i += 1024) goffL[i] = goff_g[i];
    for (int i = t; i < EE; i += 1024) gsendL[i] = (unsigned short)gsend_g[i];
    if (t < 512) { baseL[t] = basev[t]; extL[t] = extv[t]; }
    if (t < 128) bm1L[t] = b_m1[t];
    for (int i = t; i < NN * 10; i += 1024) xsL[i] = x[(long)b * (NN * 10) + i];
    for (int i = t; i < HH * 10; i += 1024) winL[i] = W_in[i];
    __syncthreads();

    // ---- input projection: hRM[r][m] ----
    for (int idx = t; idx < NN * HH; idx += 1024) {
        int r = idx >> 7, m = idx & 127;
        float acc = b_in[m];
#pragma unroll
        for (int k = 0; k < 10; k++) acc += xsL[r * 10 + k] * winL[m * 10 + k];
        hRM[r * HSTR + m] = acc;
    }
    __syncthreads();

    // ======================= 8 message-passing steps =======================
    for (int step = 0; step < NSTEPS; step++) {
        // ---------- GEMM1: hAB = h @ W1^T (cols c and 128+c) ----------
        {
            float accA[11], accB[11];
#pragma unroll
            for (int i = 0; i < 11; i++) { accA[i] = 0.f; accB[i] = 0.f; }
            for (int kc = 0; kc < 128; kc += 4) {
                float bA[4], bB[4];
#pragma unroll
                for (int j = 0; j < 4; j++) {
                    const float* Bk = W1t + (kc + j) * 256;
                    bA[j] = Bk[c];
                    bB[j] = Bk[128 + c];
                }
#pragma unroll
                for (int i = 0; i < 11; i++) {
                    if (i < nR) {
                        f32x4 a = *(const f32x4*)(hRM + (rowBase + i) * HSTR + kc);
#pragma unroll
                        for (int j = 0; j < 4; j++) {
                            accA[i] = fmaf(a[j], bA[j], accA[i]);
                            accB[i] = fmaf(a[j], bB[j], accB[i]);
                        }
                    }
                }
            }
            float* hAB = reg2;
#pragma unroll
            for (int i = 0; i < 11; i++) {
                if (i < nR) {
                    int row = rowBase + i;
                    hAB[row * ABSTR + c] = accA[i];
                    hAB[row * ABSTR + 128 + c] = accB[i];
                }
            }
        }
        __syncthreads();   // B1: hAB ready

        // ---------- edge aggregation (feature quad fq per lane) ----------
        float sv[3][4];
        {
            float bq[4];
#pragma unroll
            for (int j = 0; j < 4; j++) bq[j] = bm1L[fq + j];
#pragma unroll
            for (int s = 0; s < 3; s++) {
                int row = rW + 32 * s;
                if (row >= NN) { sv[s][0] = sv[s][1] = sv[s][2] = sv[s][3] = 0.f; continue; }
                int e0 = goffL[row], e1 = goffL[row + 1];
                f32x4 hb = *(const f32x4*)(reg2 + row * ABSTR + 128 + fq);
                float hbb[4], ac[4];
#pragma unroll
                for (int j = 0; j < 4; j++) { hbb[j] = hb[j] + bq[j]; ac[j] = 0.f; }
                for (int e = e0; e < e1; e++) {
                    int sn = gsendL[e];
                    f32x4 av = *(const f32x4*)(reg2 + sn * ABSTR + fq);
#pragma unroll
                    for (int j = 0; j < 4; j++) ac[j] += fmaxf(av[j] + hbb[j], 0.f);
                }
#pragma unroll
                for (int j = 0; j < 4; j++) sv[s][j] = ac[j];
            }
        }
        __syncthreads();   // B2: hAB reads done, reg2 reusable as smRM
        {
#pragma unroll
            for (int s = 0; s < 3; s++) {
                int row = rW + 32 * s;
                if (row >= NN) continue;
                f32x4 svv = {sv[s][0], sv[s][1], sv[s][2], sv[s][3]};
                *(f32x4*)(reg2 + row * HSTR + fq) = svv;
            }
        }
        __syncthreads();   // B3: smRM ready

        // ---------- GEMM2: gates; thread owns cols {c,128+c,256+c} ----------
        {
            float rr[11], zz[11], ni[11], nh[11];
#pragma unroll
            for (int i = 0; i < 11; i++) { rr[i] = 0.f; zz[i] = 0.f; ni[i] = 0.f; nh[i] = 0.f; }
            const float* smRM = reg2;

            // phase 1: A = sm, B rows 0..127 -> rr, zz, ni
            for (int kc = 0; kc < 128; kc += 4) {
                float bR[4], bZ[4], bN[4];
#pragma unroll
                for (int j = 0; j < 4; j++) {
                    const float* Bk = Wg2 + (kc + j) * G3;
                    bR[j] = Bk[c];
                    bZ[j] = Bk[128 + c];
                    bN[j] = Bk[256 + c];
                }
#pragma unroll
                for (int i = 0; i < 11; i++) {
                    if (i < nR) {
                        f32x4 a = *(const f32x4*)(smRM + (rowBase + i) * HSTR + kc);
#pragma unroll
                        for (int j = 0; j < 4; j++) {
                            rr[i] = fmaf(a[j], bR[j], rr[i]);
                            zz[i] = fmaf(a[j], bZ[j], zz[i]);
                            ni[i] = fmaf(a[j], bN[j], ni[i]);
                        }
                    }
                }
            }
            // phase 2: A = h, B rows 128..255 -> rr, zz, nh
            for (int kc = 0; kc < 128; kc += 4) {
                float bR[4], bZ[4], bN[4];
#pragma unroll
                for (int j = 0; j < 4; j++) {
                    const float* Bk = Wg2 + (128 + kc + j) * G3;
                    bR[j] = Bk[c];
                    bZ[j] = Bk[128 + c];
                    bN[j] = Bk[256 + c];
                }
#pragma unroll
                for (int i = 0; i < 11; i++) {
                    if (i < nR) {
                        f32x4 a = *(const f32x4*)(hRM + (rowBase + i) * HSTR + kc);
#pragma unroll
                        for (int j = 0; j < 4; j++) {
                            rr[i] = fmaf(a[j], bR[j], rr[i]);
                            zz[i] = fmaf(a[j], bZ[j], zz[i]);
                            nh[i] = fmaf(a[j], bN[j], nh[i]);
                        }
                    }
                }
            }
            __syncthreads();   // B4: all smRM/hRM reads done

            // ---- GRU epilogue: thread updates h[row][c] for its rows ----
            const float base0 = baseL[c],       ext0 = extL[c];
            const float base1 = baseL[128 + c], ext1 = extL[128 + c];
            const float base2 = baseL[256 + c], ext2 = extL[256 + c];
            const float base3 = baseL[384 + c];
#pragma unroll
            for (int i = 0; i < 11; i++) {
                if (i < nR) {
                    int row = rowBase + i;
                    float cf = (float)(goffL[row + 1] - goffL[row]);
                    float g0 = rr[i] + base0 + cf * ext0;
                    float g1 = zz[i] + base1 + cf * ext1;
                    float g2 = ni[i] + base2 + cf * ext2;
                    float g3 = nh[i] + base3;
                    float rg_ = 1.f / (1.f + __expf(-g0));
                    float z   = 1.f / (1.f + __expf(-g1));
                    float npre = g2 + rg_ * g3;
                    float ax = fabsf(npre);
                    float e  = __expf(-2.f * ax);
                    float tt = (1.f - e) / (1.f + e);
                    float n  = copysignf(tt, npre);
                    float ho = hRM[row * HSTR + c];
                    hRM[row * HSTR + c] = (1.f - z) * n + z * ho;
                }
            }
        }
        __syncthreads();   // B5: new h visible
    }

    // ======================= output head =======================
    // hid = relu(h @ W_o1^T + b_o1): thread (g,c) -> col c, its rows
    {
        float acc3[11];
#pragma unroll
        for (int i = 0; i < 11; i++) acc3[i] = 0.f;
        for (int kc = 0; kc < 128; kc += 4) {
            float bb[4];
#pragma unroll
            for (int j = 0; j < 4; j++) bb[j] = Wo1t[(kc + j) * 128 + c];
#pragma unroll
            for (int i = 0; i < 11; i++) {
                if (i < nR) {
                    f32x4 a = *(const f32x4*)(hRM + (rowBase + i) * HSTR + kc);
#pragma unroll
                    for (int j = 0; j < 4; j++) acc3[i] = fmaf(a[j], bb[j], acc3[i]);
                }
            }
        }
        float bo = b_o1[c];
        __syncthreads();   // smRM dead; reg2 -> hid
#pragma unroll
        for (int i = 0; i < 11; i++) {
            if (i < nR) {
                int row = rowBase + i;
                reg2[row * HSTR + c] = fmaxf(acc3[i] + bo, 0.f);
            }
        }
    }
    __syncthreads();
    // stage W_o2/b_o2 into hRM area (dead)
    {
        float* wo2L = hRM;
        float* bo2L = hRM + 1152;
        for (int i = t; i < 9 * HH; i += 1024) wo2L[i] = W_o2[i];
        if (t < 9) bo2L[t] = b_o2[t];
    }
    __syncthreads();
    {
        const float* wo2L = hRM;
        const float* bo2L = hRM + 1152;
        for (int idx = t; idx < NN * 9; idx += 1024) {
            int r = idx / 9, qq = idx - 9 * r;
            float acc = bo2L[qq];
            const float* hrow = reg2 + r * HSTR;
            const float* wrow = wo2L + qq * HH;
            for (int k = 0; k < HH; k++) acc = fmaf(hrow[k], wrow[k], acc);
            out[((long)b * NN + r) * 9 + qq] = acc;
        }
    }
}

// ---------------------------------------------------------------------------
extern "C" void kernel_launch(void* const* d_in, const int* in_sizes, int n_in,
                              void* d_out, int out_size, void* d_ws, size_t ws_size,
                              hipStream_t stream) {
    const float* x      = (const float*)d_in[0];
    const int* ei       = (const int*)d_in[1];
    const float* W_in   = (const float*)d_in[2];
    const float* b_in   = (const float*)d_in[3];
    const float* W_m1   = (const float*)d_in[4];
    const float* b_m1   = (const float*)d_in[5];
    const float* W_m2   = (const float*)d_in[6];
    const float* b_m2   = (const float*)d_in[7];
    const float* W_ih   = (const float*)d_in[8];
    const float* W_hh   = (const float*)d_in[9];
    const float* b_ih   = (const float*)d_in[10];
    const float* b_hh   = (const float*)d_in[11];
    const float* W_o1   = (const float*)d_in[12];
    const float* b_o1   = (const float*)d_in[13];
    const float* W_o2   = (const float*)d_in[14];
    const float* b_o2   = (const float*)d_in[15];
    float* out = (float*)d_out;

    char* ws = (char*)d_ws;
    size_t off = 0;
    auto alloc = [&](size_t bytes) -> char* {
        char* p = ws + off;
        off += (bytes + 255) & ~(size_t)255;
        return p;
    };
    float* Wc    = (float*)alloc((size_t)G3 * HH * 4);
    float* W1t   = (float*)alloc(128 * 256 * 4);
    float* Wg2   = (float*)alloc(256 * G3 * 4);
    float* Wo1t  = (float*)alloc(128 * 128 * 4);
    float* basev = (float*)alloc(512 * 4);
    float* extv  = (float*)alloc(512 * 4);
    int* goff    = (int*)alloc((NN + 1) * 4);
    int* gsend   = (int*)alloc(EE * 4);

    prep_graph<<<1, 128, 0, stream>>>(ei, goff, gsend);
    prep_wc<<<(G3 * HH + 255) / 256, 256, 0, stream>>>(W_ih, W_m2, Wc);
    prep_bias<<<2, 256, 0, stream>>>(W_ih, b_m2, b_ih, b_hh, basev, extv);
    prep_w1t<<<128, 256, 0, stream>>>(W_m1, W1t);
    prep_wg2<<<(256 * G3 + 255) / 256, 256, 0, stream>>>(Wc, W_hh, Wg2);
    prep_wo1t<<<64, 256, 0, stream>>>(W_o1, Wo1t);

    (void)hipFuncSetAttribute((const void*)fused_rrn,
                              hipFuncAttributeMaxDynamicSharedMemorySize,
                              (int)LDS_BYTES);
    fused_rrn<<<BB, 1024, LDS_BYTES, stream>>>(
        x, W_in, b_in, b_m1, W1t, Wg2, basev, extv,
        Wo1t, b_o1, W_o2, b_o2, goff, gsend, out);
}